// Round 1
// baseline (31778.406 us; speedup 1.0000x reference)
//
#include <hip/hip_runtime.h>
#include <cmath>

// Problem constants: B=256, T=512, D=1024, U=1024; M = B*T = 131072.
#define BN 256
#define TN 512
#define DN 1024
#define UN 1024

typedef _Float16 half8 __attribute__((ext_vector_type(8)));
typedef _Float16 half4v __attribute__((ext_vector_type(4)));
typedef float floatx4 __attribute__((ext_vector_type(4)));

// ---------------------------------------------------------------------------
// Phase 1: build WcT[n][k] = (kernel[k][n] * u_cur[k][n]) and
//          WpT[n][k] = (rkernel[k][n] * u_prev[k][n]) as f16, transposed.
// u column j: g_i = exp(-(i/1023 - mu_j)^2 / (2 s_j^2)), L2-normalize over i,
// scale by sqrt(1024)=32.  blockIdx.x = j, blockIdx.y = which matrix.
// ---------------------------------------------------------------------------
__global__ __launch_bounds__(256) void prep_weights(
    const float* __restrict__ kernel,   // [D][U]
    const float* __restrict__ rkernel,  // [U][U]
    const float* __restrict__ mu_c, const float* __restrict__ si_c,
    const float* __restrict__ mu_p, const float* __restrict__ si_p,
    _Float16* __restrict__ WcT,         // [U][D]
    _Float16* __restrict__ WpT)         // [U][U]
{
    __shared__ float g[1024];
    __shared__ float red[256];
    const int j = blockIdx.x;
    const bool prev = (blockIdx.y == 1);
    const float* K = prev ? rkernel : kernel;
    float mu = prev ? mu_p[j] : mu_c[j];
    float si = prev ? si_p[j] : si_c[j];
    si = fminf(fmaxf(si, 0.01f), 1.0f);
    const float inv2s2 = 1.0f / (2.0f * si * si);
    const float step = 1.0f / 1023.0f;

    float ss = 0.0f;
#pragma unroll
    for (int s = 0; s < 4; ++s) {
        int i = threadIdx.x + s * 256;
        float d = (float)i * step - mu;
        float v = expf(-d * d * inv2s2);
        g[i] = v;
        ss += v * v;
    }
    red[threadIdx.x] = ss;
    __syncthreads();
    for (int off = 128; off > 0; off >>= 1) {
        if (threadIdx.x < (unsigned)off) red[threadIdx.x] += red[threadIdx.x + off];
        __syncthreads();
    }
    const float scale = 32.0f * rsqrtf(red[0]);
    _Float16* dst = prev ? WpT : WcT;
#pragma unroll
    for (int s = 0; s < 4; ++s) {
        int i = threadIdx.x + s * 256;
        dst[(long)j * 1024 + i] = (_Float16)(K[(long)i * 1024 + j] * g[i] * scale);
    }
}

// ---------------------------------------------------------------------------
// Phase 2: Z = X @ Wc  (written into d_out).
// M=131072, N=1024, K=1024.  Block tile: 64 rows x full 1024 cols so X is
// read exactly once from HBM.  512 threads = 8 waves; wave w covers cols
// [w*128, w*128+128): 4 m-subtiles x 8 n-subtiles of 16x16x32 f16 MFMA.
// A (X, fp32) staged through LDS with fp32->f16 convert, padded stride 40.
// B fragments loaded straight from L2-resident WcT (16 B/lane contiguous).
// ---------------------------------------------------------------------------
__global__ __launch_bounds__(512, 2) void gemm_z(
    const float* __restrict__ X,        // [M][1024]
    const _Float16* __restrict__ WcT,   // [1024][1024]  (n-major)
    const float* __restrict__ bias,     // [1024]
    float* __restrict__ Z)              // [M][1024]  == d_out
{
    __shared__ _Float16 lA[64 * 40];    // 64 rows, stride 40 (pad 8)

    const int tid  = threadIdx.x;
    const int wave = tid >> 6;
    const int lane = tid & 63;
    const int q    = lane >> 4;         // 0..3
    const int ln   = lane & 15;         // 0..15
    const int ncol0 = wave * 128;
    const long m_base = (long)blockIdx.x * 64;

    const int arow = tid >> 3;          // 0..63
    const int acq  = tid & 7;           // 0..7  (each covers 4 k)

    floatx4 acc[4][8];
#pragma unroll
    for (int ms = 0; ms < 4; ++ms)
#pragma unroll
        for (int ns = 0; ns < 8; ++ns) acc[ms][ns] = (floatx4){0.f, 0.f, 0.f, 0.f};

    for (int k0 = 0; k0 < 1024; k0 += 32) {
        // stage A tile [64][32] fp32 -> f16 LDS
        float4 v = *(const float4*)(X + (m_base + arow) * 1024 + k0 + acq * 4);
        half4v hv = { (_Float16)v.x, (_Float16)v.y, (_Float16)v.z, (_Float16)v.w };
        *(half4v*)(&lA[arow * 40 + acq * 4]) = hv;
        __syncthreads();

        half8 a[4];
#pragma unroll
        for (int ms = 0; ms < 4; ++ms)
            a[ms] = *(const half8*)(&lA[(ms * 16 + ln) * 40 + q * 8]);

#pragma unroll
        for (int ns = 0; ns < 8; ++ns) {
            half8 b = *(const half8*)(WcT + (long)(ncol0 + ns * 16 + ln) * 1024 + k0 + q * 8);
#pragma unroll
            for (int ms = 0; ms < 4; ++ms)
                acc[ms][ns] = __builtin_amdgcn_mfma_f32_16x16x32_f16(a[ms], b, acc[ms][ns], 0, 0, 0);
        }
        __syncthreads();
    }

#pragma unroll
    for (int ns = 0; ns < 8; ++ns) {
        int col = ncol0 + ns * 16 + ln;
        float bs = bias[col];
#pragma unroll
        for (int ms = 0; ms < 4; ++ms) {
#pragma unroll
            for (int r = 0; r < 4; ++r) {
                long row = m_base + ms * 16 + q * 4 + r;
                Z[row * 1024 + col] = acc[ms][ns][r] + bs;
            }
        }
    }
}

// ---------------------------------------------------------------------------
// Phase 3: sequential recurrence  h_t = tanh(Z_t + h_{t-1} @ Wp), in-place
// over d_out.  16 persistent blocks, each privately owns 16 batch rows ->
// zero inter-block communication (safe vs XCD non-coherence).
// h state lives in LDS as f16 [16][1032] (pad 8 -> 2-way bank conflicts only).
// 8 waves/block; wave w computes cols [w*128, w*128+128) via 8 n-subtiles.
// Wp fragments stream from the 2 MiB L2-resident WpT.
// ---------------------------------------------------------------------------
__device__ __forceinline__ float fast_tanh(float x) {
    // tanh(x) = 1 - 2/(exp(2x)+1); handles +-inf of expf gracefully.
    return 1.0f - 2.0f / (__expf(2.0f * x) + 1.0f);
}

__global__ __launch_bounds__(512, 2) void rnn_scan(
    const _Float16* __restrict__ WpT,   // [1024][1024] (n-major)
    float* __restrict__ Zout)           // [B][T][U], Z in, h out (in place)
{
    __shared__ _Float16 h[16 * 1032];

    const int tid  = threadIdx.x;
    const int wave = tid >> 6;
    const int lane = tid & 63;
    const int q    = lane >> 4;
    const int ln   = lane & 15;
    const int ncol0 = wave * 128;
    const int bi   = blockIdx.x;        // batch group: rows bi*16 .. bi*16+15

    for (int i = tid; i < 16 * 1032; i += 512) h[i] = (_Float16)0.0f;
    __syncthreads();

    for (int t = 0; t < TN; ++t) {
        floatx4 acc[8];
#pragma unroll
        for (int ns = 0; ns < 8; ++ns) acc[ns] = (floatx4){0.f, 0.f, 0.f, 0.f};

        for (int k0 = 0; k0 < 1024; k0 += 32) {
            half8 a = *(const half8*)(&h[ln * 1032 + k0 + q * 8]);
#pragma unroll
            for (int ns = 0; ns < 8; ++ns) {
                half8 b = *(const half8*)(WpT + (long)(ncol0 + ns * 16 + ln) * 1024 + k0 + q * 8);
                acc[ns] = __builtin_amdgcn_mfma_f32_16x16x32_f16(a, b, acc[ns], 0, 0, 0);
            }
        }
        __syncthreads();   // all waves done reading h for this step

#pragma unroll
        for (int ns = 0; ns < 8; ++ns) {
            int col = ncol0 + ns * 16 + ln;
#pragma unroll
            for (int r = 0; r < 4; ++r) {
                int m = q * 4 + r;
                long gidx = ((long)(bi * 16 + m) * TN + t) * 1024 + col;
                float hn = fast_tanh(Zout[gidx] + acc[ns][r]);
                Zout[gidx] = hn;
                h[m * 1032 + col] = (_Float16)hn;
            }
        }
        __syncthreads();   // h fully updated before next step's reads
    }
}

// ---------------------------------------------------------------------------
extern "C" void kernel_launch(void* const* d_in, const int* in_sizes, int n_in,
                              void* d_out, int out_size, void* d_ws, size_t ws_size,
                              hipStream_t stream) {
    (void)in_sizes; (void)n_in; (void)out_size; (void)ws_size;
    const float* X    = (const float*)d_in[0];
    // d_in[1] = h0 (zeros, unused)
    const float* K    = (const float*)d_in[2];
    const float* RK   = (const float*)d_in[3];
    const float* bias = (const float*)d_in[4];
    const float* muc  = (const float*)d_in[5];
    const float* sic  = (const float*)d_in[6];
    const float* mup  = (const float*)d_in[7];
    const float* sip  = (const float*)d_in[8];
    float* out = (float*)d_out;

    _Float16* WcT = (_Float16*)d_ws;            // 2 MiB
    _Float16* WpT = WcT + 1024 * 1024;          // 2 MiB

    prep_weights<<<dim3(1024, 2), 256, 0, stream>>>(K, RK, muc, sic, mup, sip, WcT, WpT);
    gemm_z<<<dim3((BN * TN) / 64), 512, 0, stream>>>(X, WcT, bias, out);
    rnn_scan<<<dim3(BN / 16), 512, 0, stream>>>(WpT, out);
}